// Round 9
// baseline (184.917 us; speedup 1.0000x reference)
//
#include <hip/hip_runtime.h>

#define BN_EPS 0.001f
#define CAP 32   // deg = 1 + Poisson(~9); P(deg >= 32) ~ 1e-22 -> safe
#define NPART 8  // node partitions (match 8 XCDs; bid%8 ~ XCD round-robin heuristic)
#define SEGE 2048  // edges per scatter segment (256 threads x 8)

typedef __attribute__((ext_vector_type(8))) short bf16x8;
typedef __attribute__((ext_vector_type(4))) float f32x4;
typedef __attribute__((ext_vector_type(2))) float f32x2;

__device__ __forceinline__ unsigned short f2bf(float f) {
  unsigned u = __float_as_uint(f);
  u += 0x7fffu + ((u >> 16) & 1u);
  return (unsigned short)(u >> 16);
}
__device__ __forceinline__ unsigned scale2(unsigned u, float s) {
  float lo = __uint_as_float(u << 16) * s;
  float hi = __uint_as_float(u & 0xffff0000u) * s;
  return (((unsigned)f2bf(hi)) << 16) | (unsigned)f2bf(lo);
}

// ---------- FUSED: interleaved 5:2 partitioned-scatter / MFMA-gemm ----------
// X loads are NONTEMPORAL (ext_vector_type for the builtin): X is 51.2MB of
// single-use stream; without nt it flushes each XCD L2 and evicts the scatter
// partition's dirty ell/cnt lines between partial writes (the remaining ~50MB
// write amplification).
__global__ __launch_bounds__(256) void k_fused(
    const float* __restrict__ X, const float* __restrict__ W,
    const float* __restrict__ B, unsigned short* __restrict__ hb, int N, int Gg,
    const int2* __restrict__ ei, int* __restrict__ cnt,
    int* __restrict__ ell_t, int E, int Gs) {
  __shared__ float WtF[4096];  // 16 KB: Wt[col][k] bf16, XOR-swizzled

  int g = blockIdx.x / 7;
  int r = blockIdx.x % 7;
  int tid = threadIdx.x;

  if (r >= 2) {
    // ----- scatter role: partition p = u&7, segment = u>>3 -----
    int u = g * 5 + (r - 2);
    if (u >= Gs) return;
    int p   = u & (NPART - 1);
    int seg = u >> 3;
    int lo = (int)((size_t)p * N / NPART);
    int hi = (int)((size_t)(p + 1) * N / NPART);
    int base = seg * SEGE;
    #pragma unroll
    for (int i = 0; i < 8; ++i) {
      int e = base + i * 256 + tid;
      if (e < E) {
        int2 sd = ei[e];
        if (sd.x >= lo && sd.x < hi) {
          int pos = atomicAdd(&cnt[sd.x], 1);
          if (pos < CAP) ell_t[(size_t)pos * N + sd.x] = sd.y;
        }
      }
    }
    return;
  }

  // ----- gemm role: hb = bf16(X@W + b) via MFMA, 64 rows x 64 cols per block -----
  int tile = g * 2 + r;
  if (tile >= Gg) return;

  char* Wt = (char*)WtF;
  const float4* W4 = (const float4*)W;
  for (int i = tid; i < 2048; i += 256) {
    float4 v = W4[i];
    int k = i >> 4;
    int col0 = (i & 15) << 2;
    int kb2 = k << 1;
    *(unsigned short*)(Wt + (((col0 + 0) << 8) | (kb2 ^ (((col0 + 0) & 7) << 4)))) = f2bf(v.x);
    *(unsigned short*)(Wt + (((col0 + 1) << 8) | (kb2 ^ (((col0 + 1) & 7) << 4)))) = f2bf(v.y);
    *(unsigned short*)(Wt + (((col0 + 2) << 8) | (kb2 ^ (((col0 + 2) & 7) << 4)))) = f2bf(v.z);
    *(unsigned short*)(Wt + (((col0 + 3) << 8) | (kb2 ^ (((col0 + 3) & 7) << 4)))) = f2bf(v.w);
  }
  __syncthreads();

  int lane = tid & 63;
  int w = tid >> 6;
  int l15 = lane & 15;
  int lk = lane >> 4;

  int row0 = tile * 64;
  int rA = row0 + w * 16 + l15;
  bool rowok = rA < N;
  const float* xp = X + (size_t)rA * 128 + (lk << 3);

  f32x4 acc[4];
  #pragma unroll
  for (int n = 0; n < 4; ++n) {
    float bv = B[(n << 4) + l15];
    acc[n] = (f32x4){bv, bv, bv, bv};
  }

  #pragma unroll
  for (int kb = 0; kb < 4; ++kb) {
    bf16x8 af = {0, 0, 0, 0, 0, 0, 0, 0};
    if (rowok) {
      const f32x4* xq = (const f32x4*)(xp + kb * 32);
      f32x4 x0 = __builtin_nontemporal_load(xq);      // nt: single-use stream
      f32x4 x1 = __builtin_nontemporal_load(xq + 1);
      af[0] = (short)f2bf(x0.x); af[1] = (short)f2bf(x0.y);
      af[2] = (short)f2bf(x0.z); af[3] = (short)f2bf(x0.w);
      af[4] = (short)f2bf(x1.x); af[5] = (short)f2bf(x1.y);
      af[6] = (short)f2bf(x1.z); af[7] = (short)f2bf(x1.w);
    }
    int kbyte = (kb << 6) | (lk << 4);
    #pragma unroll
    for (int n = 0; n < 4; ++n) {
      int col = (n << 4) + l15;
      bf16x8 bfr = *(const bf16x8*)(Wt + ((col << 8) | (kbyte ^ ((col & 7) << 4))));
      acc[n] = __builtin_amdgcn_mfma_f32_16x16x32_bf16(af, bfr, acc[n], 0, 0, 0);
    }
  }

  // C/D layout (verified m89/m91): col = lane&15, row = (lane>>4)*4 + reg
  int rbase = row0 + w * 16 + (lk << 2);
  #pragma unroll
  for (int n = 0; n < 4; ++n) {
    #pragma unroll
    for (int q = 0; q < 4; ++q) {
      int row = rbase + q;
      if (row < N) hb[(size_t)row * 64 + (n << 4) + l15] = f2bf(acc[n][q]);
    }
  }
}

// ---------- scale pass: hbs = bf16(rsqrt(deg) * hb), dense, ~26MB traffic ----------
__global__ __launch_bounds__(256) void k_scale(const unsigned int* __restrict__ hb32,
                                               const int* __restrict__ cnt,
                                               unsigned int* __restrict__ hbs32, int N) {
  int t = blockIdx.x * 256 + threadIdx.x;
  int node = t >> 3;           // 8 threads per node (8 x uint4 = 128B row)
  int q = t & 7;
  if (node >= N) return;
  int c = cnt[node];
  float s = rsqrtf((float)((c > 0) ? c : 1));
  uint4 v = ((const uint4*)(hb32 + (size_t)node * 32))[q];
  v.x = scale2(v.x, s); v.y = scale2(v.y, s);
  v.z = scale2(v.z, s); v.w = scale2(v.w, s);
  ((uint4*)(hbs32 + (size_t)node * 32))[q] = v;
}

// ---------- aggregate + self + BN from TRANSPOSED ELL ----------
__global__ __launch_bounds__(256) void k_agg2(const int* __restrict__ cnt,
                                              const int* __restrict__ ell_t,
                                              const unsigned int* __restrict__ hb32,
                                              const unsigned int* __restrict__ hbs32,
                                              const float* __restrict__ gamma,
                                              const float* __restrict__ beta,
                                              const float* __restrict__ mean,
                                              const float* __restrict__ var,
                                              float* __restrict__ out, int N) {
  __shared__ int lds_dst[CAP * 64];   // [p][j] 8 KB
  __shared__ int lds_cnt[64];

  int tid = threadIdx.x;
  int node0 = blockIdx.x * 64;

  if (tid < 64) {
    int n = node0 + tid;
    lds_cnt[tid] = (n < N) ? cnt[n] : 0;
  }
  for (int i = tid; i < CAP * 64; i += 256) {
    int j = i & 63;
    int p = i >> 6;
    int n = node0 + j;
    lds_dst[i] = (n < N) ? ell_t[(size_t)p * N + n] : 0;
  }
  __syncthreads();

  int hw = tid >> 5;
  int fp = tid & 31;

  float2 gm = *(const float2*)&gamma[fp * 2];
  float2 bt = *(const float2*)&beta[fp * 2];
  float2 mn = *(const float2*)&mean[fp * 2];
  float2 vr = *(const float2*)&var[fp * 2];
  float gsx = gm.x * rsqrtf(vr.x + BN_EPS);
  float gsy = gm.y * rsqrtf(vr.y + BN_EPS);

  #pragma unroll
  for (int t = 0; t < 8; ++t) {
    int j = hw * 8 + t;
    int node = node0 + j;
    if (node >= N) continue;
    int c0 = lds_cnt[j];
    int c = (c0 < CAP) ? c0 : CAP;
    unsigned us = hb32[(size_t)node * 32 + fp];   // self row (raw h), issue early

    float ax = 0.f, ay = 0.f;
    int q = 0;
    for (; q + 8 <= c; q += 8) {
      int d[8];
      #pragma unroll
      for (int i = 0; i < 8; ++i) {
        int dr = lds_dst[(q + i) * 64 + j];
        d[i] = ((unsigned)dr < (unsigned)N) ? dr : 0;
      }
      unsigned u[8];
      #pragma unroll
      for (int i = 0; i < 8; ++i) u[i] = hbs32[(size_t)d[i] * 32 + fp];
      #pragma unroll
      for (int i = 0; i < 8; ++i) {
        ax += __uint_as_float(u[i] << 16);
        ay += __uint_as_float(u[i] & 0xffff0000u);
      }
    }
    if (q + 4 <= c) {
      int d0 = lds_dst[(q + 0) * 64 + j]; d0 = ((unsigned)d0 < (unsigned)N) ? d0 : 0;
      int d1 = lds_dst[(q + 1) * 64 + j]; d1 = ((unsigned)d1 < (unsigned)N) ? d1 : 0;
      int d2 = lds_dst[(q + 2) * 64 + j]; d2 = ((unsigned)d2 < (unsigned)N) ? d2 : 0;
      int d3 = lds_dst[(q + 3) * 64 + j]; d3 = ((unsigned)d3 < (unsigned)N) ? d3 : 0;
      unsigned u0 = hbs32[(size_t)d0 * 32 + fp];
      unsigned u1 = hbs32[(size_t)d1 * 32 + fp];
      unsigned u2 = hbs32[(size_t)d2 * 32 + fp];
      unsigned u3 = hbs32[(size_t)d3 * 32 + fp];
      ax += __uint_as_float(u0 << 16); ay += __uint_as_float(u0 & 0xffff0000u);
      ax += __uint_as_float(u1 << 16); ay += __uint_as_float(u1 & 0xffff0000u);
      ax += __uint_as_float(u2 << 16); ay += __uint_as_float(u2 & 0xffff0000u);
      ax += __uint_as_float(u3 << 16); ay += __uint_as_float(u3 & 0xffff0000u);
      q += 4;
    }
    for (; q < c; ++q) {
      int dq = lds_dst[q * 64 + j];
      dq = ((unsigned)dq < (unsigned)N) ? dq : 0;
      unsigned u = hbs32[(size_t)dq * 32 + fp];
      ax += __uint_as_float(u << 16);
      ay += __uint_as_float(u & 0xffff0000u);
    }

    float hx = __uint_as_float(us << 16);
    float hy = __uint_as_float(us & 0xffff0000u);
    float degf = (float)c0;
    float isd_n = rsqrtf((float)((c0 > 0) ? c0 : 1));
    float rx = 0.5f * (isd_n * ax + degf * hx);
    float ry = 0.5f * (isd_n * ay + degf * hy);

    f32x2 o;
    o.x = (rx - mn.x) * gsx + bt.x;
    o.y = (ry - mn.y) * gsy + bt.y;
    __builtin_nontemporal_store(o, (f32x2*)&out[(size_t)node * 64 + fp * 2]);  // nt: never re-read
  }
}

// ---------- fallback (ws too small for hbs): gather raw hb + per-dst scale ----------
__global__ __launch_bounds__(256) void k_agg2_g(const int* __restrict__ cnt,
                                                const int* __restrict__ ell_t,
                                                const unsigned int* __restrict__ hb32,
                                                const float* __restrict__ gamma,
                                                const float* __restrict__ beta,
                                                const float* __restrict__ mean,
                                                const float* __restrict__ var,
                                                float* __restrict__ out, int N) {
  __shared__ int lds_dst[CAP * 64];
  __shared__ int lds_cnt[64];

  int tid = threadIdx.x;
  int node0 = blockIdx.x * 64;

  if (tid < 64) {
    int n = node0 + tid;
    lds_cnt[tid] = (n < N) ? cnt[n] : 0;
  }
  for (int i = tid; i < CAP * 64; i += 256) {
    int j = i & 63;
    int p = i >> 6;
    int n = node0 + j;
    lds_dst[i] = (n < N) ? ell_t[(size_t)p * N + n] : 0;
  }
  __syncthreads();

  int hw = tid >> 5;
  int fp = tid & 31;

  float2 gm = *(const float2*)&gamma[fp * 2];
  float2 bt = *(const float2*)&beta[fp * 2];
  float2 mn = *(const float2*)&mean[fp * 2];
  float2 vr = *(const float2*)&var[fp * 2];
  float gsx = gm.x * rsqrtf(vr.x + BN_EPS);
  float gsy = gm.y * rsqrtf(vr.y + BN_EPS);

  for (int t = 0; t < 8; ++t) {
    int j = hw * 8 + t;
    int node = node0 + j;
    if (node >= N) continue;
    int c0 = lds_cnt[j];
    int c = (c0 < CAP) ? c0 : CAP;
    unsigned us = hb32[(size_t)node * 32 + fp];

    float ax = 0.f, ay = 0.f;
    int q = 0;
    for (; q + 4 <= c; q += 4) {
      int d0 = lds_dst[(q + 0) * 64 + j]; d0 = ((unsigned)d0 < (unsigned)N) ? d0 : 0;
      int d1 = lds_dst[(q + 1) * 64 + j]; d1 = ((unsigned)d1 < (unsigned)N) ? d1 : 0;
      int d2 = lds_dst[(q + 2) * 64 + j]; d2 = ((unsigned)d2 < (unsigned)N) ? d2 : 0;
      int d3 = lds_dst[(q + 3) * 64 + j]; d3 = ((unsigned)d3 < (unsigned)N) ? d3 : 0;
      float s0 = rsqrtf((float)max(cnt[d0], 1));
      float s1 = rsqrtf((float)max(cnt[d1], 1));
      float s2 = rsqrtf((float)max(cnt[d2], 1));
      float s3 = rsqrtf((float)max(cnt[d3], 1));
      unsigned u0 = hb32[(size_t)d0 * 32 + fp];
      unsigned u1 = hb32[(size_t)d1 * 32 + fp];
      unsigned u2 = hb32[(size_t)d2 * 32 + fp];
      unsigned u3 = hb32[(size_t)d3 * 32 + fp];
      ax = fmaf(s0, __uint_as_float(u0 << 16), ax);
      ay = fmaf(s0, __uint_as_float(u0 & 0xffff0000u), ay);
      ax = fmaf(s1, __uint_as_float(u1 << 16), ax);
      ay = fmaf(s1, __uint_as_float(u1 & 0xffff0000u), ay);
      ax = fmaf(s2, __uint_as_float(u2 << 16), ax);
      ay = fmaf(s2, __uint_as_float(u2 & 0xffff0000u), ay);
      ax = fmaf(s3, __uint_as_float(u3 << 16), ax);
      ay = fmaf(s3, __uint_as_float(u3 & 0xffff0000u), ay);
    }
    for (; q < c; ++q) {
      int dq = lds_dst[q * 64 + j];
      dq = ((unsigned)dq < (unsigned)N) ? dq : 0;
      float sq = rsqrtf((float)max(cnt[dq], 1));
      unsigned u = hb32[(size_t)dq * 32 + fp];
      ax = fmaf(sq, __uint_as_float(u << 16), ax);
      ay = fmaf(sq, __uint_as_float(u & 0xffff0000u), ay);
    }

    float hx = __uint_as_float(us << 16);
    float hy = __uint_as_float(us & 0xffff0000u);
    float degf = (float)c0;
    float isd_n = rsqrtf((float)((c0 > 0) ? c0 : 1));
    float rx = 0.5f * (isd_n * ax + degf * hx);
    float ry = 0.5f * (isd_n * ay + degf * hy);

    f32x2 o;
    o.x = (rx - mn.x) * gsx + bt.x;
    o.y = (ry - mn.y) * gsy + bt.y;
    __builtin_nontemporal_store(o, (f32x2*)&out[(size_t)node * 64 + fp * 2]);
  }
}

extern "C" void kernel_launch(void* const* d_in, const int* in_sizes, int n_in,
                              void* d_out, int out_size, void* d_ws, size_t ws_size,
                              hipStream_t stream) {
  const float* X     = (const float*)d_in[0];
  const float* W     = (const float*)d_in[1];
  const float* B     = (const float*)d_in[2];
  const float* gamma = (const float*)d_in[3];
  const float* beta  = (const float*)d_in[4];
  const float* mean  = (const float*)d_in[5];
  const float* var   = (const float*)d_in[6];
  const int2*  ei    = (const int2*)d_in[7];

  int N = in_sizes[0] / 128;
  int E = in_sizes[7] / 2;
  float* out = (float*)d_out;

  size_t hb_elems = (size_t)N * 64;
  size_t need_hbs = hb_elems * 2 * 2 + (size_t)N * CAP * 4 + (size_t)N * 4;

  int Gs = NPART * ((E + SEGE - 1) / SEGE);   // partitioned scatter units
  int Gg = (N + 63) / 64;                     // gemm tiles
  int g7 = (Gg + 1) / 2;
  int g5 = (Gs + 4) / 5;
  int groups = (g7 > g5) ? g7 : g5;
  int Ga = (N + 63) / 64;                     // agg blocks (64 nodes each)

  if (ws_size >= need_hbs) {
    // layout: hb | hbs | ell_t | cnt
    unsigned short* hb  = (unsigned short*)d_ws;
    unsigned short* hbs = hb + hb_elems;
    int*            ell = (int*)(hbs + hb_elems);
    int*            cnt = ell + (size_t)N * CAP;

    (void)hipMemsetAsync(cnt, 0, (size_t)N * sizeof(int), stream);
    k_fused<<<groups * 7, 256, 0, stream>>>(X, W, B, hb, N, Gg, ei, cnt, ell, E, Gs);
    k_scale<<<(N * 8 + 255) / 256, 256, 0, stream>>>((const unsigned int*)hb, cnt,
                                                     (unsigned int*)hbs, N);
    k_agg2<<<Ga, 256, 0, stream>>>(cnt, ell, (const unsigned int*)hb,
                                   (const unsigned int*)hbs,
                                   gamma, beta, mean, var, out, N);
  } else {
    // layout: hb | ell_t | cnt
    unsigned short* hb  = (unsigned short*)d_ws;
    int*            ell = (int*)(hb + hb_elems);
    int*            cnt = ell + (size_t)N * CAP;

    (void)hipMemsetAsync(cnt, 0, (size_t)N * sizeof(int), stream);
    k_fused<<<groups * 7, 256, 0, stream>>>(X, W, B, hb, N, Gg, ei, cnt, ell, E, Gs);
    k_agg2_g<<<Ga, 256, 0, stream>>>(cnt, ell, (const unsigned int*)hb,
                                     gamma, beta, mean, var, out, N);
  }
}

// Round 10
// 178.838 us; speedup vs baseline: 1.0340x; 1.0340x over previous
//
#include <hip/hip_runtime.h>

#define BN_EPS 0.001f
#define CAP 32    // deg = 1 + Poisson(~9); P(deg >= 32) ~ 1e-22 -> safe
#define NPART 8   // node partitions, bound to XCD via p = blockIdx&7 (heuristic)
#define SEGE 4096 // edges per scatter segment (256 threads x 16 edges)

typedef __attribute__((ext_vector_type(8))) short bf16x8;
typedef __attribute__((ext_vector_type(4))) float f32x4;

__device__ __forceinline__ unsigned short f2bf(float f) {
  unsigned u = __float_as_uint(f);
  u += 0x7fffu + ((u >> 16) & 1u);
  return (unsigned short)(u >> 16);
}

// ---------- FUSED: XCD-bound partitioned scatter + MFMA gemm, 16-block groups ----------
// Group of 16 consecutive blocks: slots 0-7 scatter (partition p = bid&7 -> under
// round-robin dispatch all of partition p's blocks share XCD p's L2, so each dirty
// ell/cnt line accumulates ALL its slot-writes in ONE private L2 before writeback),
// slots 8-15 gemm tiles. Cross-XCD line sharing was the ~3.5x write amplification.
__global__ __launch_bounds__(256) void k_fused(
    const float* __restrict__ X, const float* __restrict__ W,
    const float* __restrict__ B, unsigned short* __restrict__ hb, int N, int Gg,
    const int2* __restrict__ ei, int* __restrict__ cnt,
    int* __restrict__ ell_t, int E) {
  __shared__ float WtF[4096];  // 16 KB: Wt[col][k] bf16, XOR-swizzled

  int bid = blockIdx.x;
  int tid = threadIdx.x;
  int gid = bid >> 4;
  int slot = bid & 15;

  if (slot < 8) {
    // ----- scatter role: partition p = bid&7 (XCD-bound), segment = gid -----
    int p = slot;
    int lo = (int)((long long)p * N / NPART);
    int hi = (int)((long long)(p + 1) * N / NPART);
    const int4* e4 = (const int4*)ei;
    int n4 = E >> 1;
    int base4 = gid * (SEGE / 2);
    #pragma unroll
    for (int i = 0; i < 8; ++i) {
      int q = base4 + i * 256 + tid;
      if (q < n4) {
        int4 v = e4[q];                   // 2 edges, coalesced
        if (v.x >= lo && v.x < hi) {
          int pos = atomicAdd(&cnt[v.x], 1);
          if (pos < CAP) ell_t[(size_t)pos * N + v.x] = v.y;
        }
        if (v.z >= lo && v.z < hi) {
          int pos = atomicAdd(&cnt[v.z], 1);
          if (pos < CAP) ell_t[(size_t)pos * N + v.z] = v.w;
        }
      }
    }
    if ((E & 1) && gid == 0 && tid == 0) {
      int2 sd = ei[E - 1];
      if (sd.x >= lo && sd.x < hi) {
        int pos = atomicAdd(&cnt[sd.x], 1);
        if (pos < CAP) ell_t[(size_t)pos * N + sd.x] = sd.y;
      }
    }
    return;
  }

  // ----- gemm role: hb = bf16(X@W + b) via MFMA, 64 rows x 64 cols per block -----
  int tile = gid * 8 + (slot - 8);
  if (tile >= Gg) return;

  char* Wt = (char*)WtF;
  const float4* W4 = (const float4*)W;
  for (int i = tid; i < 2048; i += 256) {
    float4 v = W4[i];
    int k = i >> 4;
    int col0 = (i & 15) << 2;
    int kb2 = k << 1;
    *(unsigned short*)(Wt + (((col0 + 0) << 8) | (kb2 ^ (((col0 + 0) & 7) << 4)))) = f2bf(v.x);
    *(unsigned short*)(Wt + (((col0 + 1) << 8) | (kb2 ^ (((col0 + 1) & 7) << 4)))) = f2bf(v.y);
    *(unsigned short*)(Wt + (((col0 + 2) << 8) | (kb2 ^ (((col0 + 2) & 7) << 4)))) = f2bf(v.z);
    *(unsigned short*)(Wt + (((col0 + 3) << 8) | (kb2 ^ (((col0 + 3) & 7) << 4)))) = f2bf(v.w);
  }
  __syncthreads();

  int lane = tid & 63;
  int w = tid >> 6;
  int l15 = lane & 15;
  int lk = lane >> 4;

  int row0 = tile * 64;
  int rA = row0 + w * 16 + l15;
  bool rowok = rA < N;
  const float* xp = X + (size_t)rA * 128 + (lk << 3);

  f32x4 acc[4];
  #pragma unroll
  for (int n = 0; n < 4; ++n) {
    float bv = B[(n << 4) + l15];
    acc[n] = (f32x4){bv, bv, bv, bv};
  }

  #pragma unroll
  for (int kb = 0; kb < 4; ++kb) {
    bf16x8 af = {0, 0, 0, 0, 0, 0, 0, 0};
    if (rowok) {
      float4 x0 = *(const float4*)(xp + kb * 32);
      float4 x1 = *(const float4*)(xp + kb * 32 + 4);
      af[0] = (short)f2bf(x0.x); af[1] = (short)f2bf(x0.y);
      af[2] = (short)f2bf(x0.z); af[3] = (short)f2bf(x0.w);
      af[4] = (short)f2bf(x1.x); af[5] = (short)f2bf(x1.y);
      af[6] = (short)f2bf(x1.z); af[7] = (short)f2bf(x1.w);
    }
    int kbyte = (kb << 6) | (lk << 4);
    #pragma unroll
    for (int n = 0; n < 4; ++n) {
      int col = (n << 4) + l15;
      bf16x8 bfr = *(const bf16x8*)(Wt + ((col << 8) | (kbyte ^ ((col & 7) << 4))));
      acc[n] = __builtin_amdgcn_mfma_f32_16x16x32_bf16(af, bfr, acc[n], 0, 0, 0);
    }
  }

  // C/D layout (verified m89/m91): col = lane&15, row = (lane>>4)*4 + reg
  int rbase = row0 + w * 16 + (lk << 2);
  #pragma unroll
  for (int n = 0; n < 4; ++n) {
    #pragma unroll
    for (int q = 0; q < 4; ++q) {
      int row = rbase + q;
      if (row < N) hb[(size_t)row * 64 + (n << 4) + l15] = f2bf(acc[n][q]);
    }
  }
}

// ---------- aggregate + self + BN from TRANSPOSED ELL, per-edge cnt lookup ----------
// cnt is 400KB -> L2-resident, so the per-edge cnt[d] broadcast load + rsqrt is
// cheap; this removes the k_scale pass + hbs buffer + one dispatch gap.
__global__ __launch_bounds__(256) void k_agg(const int* __restrict__ cnt,
                                             const int* __restrict__ ell_t,
                                             const unsigned int* __restrict__ hb32,
                                             const float* __restrict__ gamma,
                                             const float* __restrict__ beta,
                                             const float* __restrict__ mean,
                                             const float* __restrict__ var,
                                             float* __restrict__ out, int N) {
  __shared__ int lds_dst[CAP * 64];   // [p][j] 8 KB
  __shared__ int lds_cnt[64];

  int tid = threadIdx.x;
  int node0 = blockIdx.x * 64;

  if (tid < 64) {
    int n = node0 + tid;
    lds_cnt[tid] = (n < N) ? cnt[n] : 0;
  }
  for (int i = tid; i < CAP * 64; i += 256) {
    int j = i & 63;
    int p = i >> 6;
    int n = node0 + j;
    lds_dst[i] = (n < N) ? ell_t[(size_t)p * N + n] : 0;
  }
  __syncthreads();

  int hw = tid >> 5;
  int fp = tid & 31;

  float2 gm = *(const float2*)&gamma[fp * 2];
  float2 bt = *(const float2*)&beta[fp * 2];
  float2 mn = *(const float2*)&mean[fp * 2];
  float2 vr = *(const float2*)&var[fp * 2];
  float gsx = gm.x * rsqrtf(vr.x + BN_EPS);
  float gsy = gm.y * rsqrtf(vr.y + BN_EPS);

  #pragma unroll
  for (int t = 0; t < 8; ++t) {
    int j = hw * 8 + t;
    int node = node0 + j;
    if (node >= N) continue;
    int c0 = lds_cnt[j];
    int c = (c0 < CAP) ? c0 : CAP;
    unsigned us = hb32[(size_t)node * 32 + fp];   // self row, issue early

    float ax = 0.f, ay = 0.f;
    int q = 0;
    for (; q + 8 <= c; q += 8) {
      int d[8];
      #pragma unroll
      for (int i = 0; i < 8; ++i) {
        int dr = lds_dst[(q + i) * 64 + j];
        d[i] = ((unsigned)dr < (unsigned)N) ? dr : 0;
      }
      int cc[8];
      #pragma unroll
      for (int i = 0; i < 8; ++i) cc[i] = cnt[d[i]];      // L2-resident broadcast
      unsigned u[8];
      #pragma unroll
      for (int i = 0; i < 8; ++i) u[i] = hb32[(size_t)d[i] * 32 + fp];
      #pragma unroll
      for (int i = 0; i < 8; ++i) {
        float s = rsqrtf((float)((cc[i] > 0) ? cc[i] : 1));
        ax = fmaf(s, __uint_as_float(u[i] << 16), ax);
        ay = fmaf(s, __uint_as_float(u[i] & 0xffff0000u), ay);
      }
    }
    if (q + 4 <= c) {
      int d0 = lds_dst[(q + 0) * 64 + j]; d0 = ((unsigned)d0 < (unsigned)N) ? d0 : 0;
      int d1 = lds_dst[(q + 1) * 64 + j]; d1 = ((unsigned)d1 < (unsigned)N) ? d1 : 0;
      int d2 = lds_dst[(q + 2) * 64 + j]; d2 = ((unsigned)d2 < (unsigned)N) ? d2 : 0;
      int d3 = lds_dst[(q + 3) * 64 + j]; d3 = ((unsigned)d3 < (unsigned)N) ? d3 : 0;
      int c0_ = cnt[d0], c1_ = cnt[d1], c2_ = cnt[d2], c3_ = cnt[d3];
      unsigned u0 = hb32[(size_t)d0 * 32 + fp];
      unsigned u1 = hb32[(size_t)d1 * 32 + fp];
      unsigned u2 = hb32[(size_t)d2 * 32 + fp];
      unsigned u3 = hb32[(size_t)d3 * 32 + fp];
      float s0 = rsqrtf((float)((c0_ > 0) ? c0_ : 1));
      float s1 = rsqrtf((float)((c1_ > 0) ? c1_ : 1));
      float s2 = rsqrtf((float)((c2_ > 0) ? c2_ : 1));
      float s3 = rsqrtf((float)((c3_ > 0) ? c3_ : 1));
      ax = fmaf(s0, __uint_as_float(u0 << 16), ax);
      ay = fmaf(s0, __uint_as_float(u0 & 0xffff0000u), ay);
      ax = fmaf(s1, __uint_as_float(u1 << 16), ax);
      ay = fmaf(s1, __uint_as_float(u1 & 0xffff0000u), ay);
      ax = fmaf(s2, __uint_as_float(u2 << 16), ax);
      ay = fmaf(s2, __uint_as_float(u2 & 0xffff0000u), ay);
      ax = fmaf(s3, __uint_as_float(u3 << 16), ax);
      ay = fmaf(s3, __uint_as_float(u3 & 0xffff0000u), ay);
      q += 4;
    }
    for (; q < c; ++q) {
      int dq = lds_dst[q * 64 + j];
      dq = ((unsigned)dq < (unsigned)N) ? dq : 0;
      int cq = cnt[dq];
      unsigned u = hb32[(size_t)dq * 32 + fp];
      float sq = rsqrtf((float)((cq > 0) ? cq : 1));
      ax = fmaf(sq, __uint_as_float(u << 16), ax);
      ay = fmaf(sq, __uint_as_float(u & 0xffff0000u), ay);
    }

    float hx = __uint_as_float(us << 16);
    float hy = __uint_as_float(us & 0xffff0000u);
    float degf = (float)c0;
    float isd_n = rsqrtf((float)((c0 > 0) ? c0 : 1));
    float rx = 0.5f * (isd_n * ax + degf * hx);
    float ry = 0.5f * (isd_n * ay + degf * hy);

    float2 o;
    o.x = (rx - mn.x) * gsx + bt.x;
    o.y = (ry - mn.y) * gsy + bt.y;
    *(float2*)&out[(size_t)node * 64 + fp * 2] = o;
  }
}

extern "C" void kernel_launch(void* const* d_in, const int* in_sizes, int n_in,
                              void* d_out, int out_size, void* d_ws, size_t ws_size,
                              hipStream_t stream) {
  const float* X     = (const float*)d_in[0];
  const float* W     = (const float*)d_in[1];
  const float* B     = (const float*)d_in[2];
  const float* gamma = (const float*)d_in[3];
  const float* beta  = (const float*)d_in[4];
  const float* mean  = (const float*)d_in[5];
  const float* var   = (const float*)d_in[6];
  const int2*  ei    = (const int2*)d_in[7];

  int N = in_sizes[0] / 128;
  int E = in_sizes[7] / 2;
  float* out = (float*)d_out;

  // workspace: hb (N*64 bf16 = 12.8MB) | ell_t (N*CAP int = 12.8MB) | cnt (N int)
  unsigned short* hb  = (unsigned short*)d_ws;
  int*            ell = (int*)(hb + (size_t)N * 64);
  int*            cnt = ell + (size_t)N * CAP;

  (void)hipMemsetAsync(cnt, 0, (size_t)N * sizeof(int), stream);

  int Gg = (N + 63) / 64;                       // gemm tiles
  int nsegs = (E + SEGE - 1) / SEGE;            // scatter segments (x8 partitions)
  int ngg = (Gg + 7) / 8;                       // gemm groups
  int ngroups = (nsegs > ngg) ? nsegs : ngg;
  k_fused<<<ngroups * 16, 256, 0, stream>>>(X, W, B, hb, N, Gg, ei, cnt, ell, E);

  int Ga = (N + 63) / 64;                       // agg blocks (64 nodes each)
  k_agg<<<Ga, 256, 0, stream>>>(cnt, ell, (const unsigned int*)hb,
                                gamma, beta, mean, var, out, N);
}

// Round 11
// 175.987 us; speedup vs baseline: 1.0507x; 1.0162x over previous
//
#include <hip/hip_runtime.h>

#define BN_EPS 0.001f
#define CAP 32    // deg = 1 + Poisson(~9); P(deg >= 32) ~ 1e-22 -> safe
#define NPART 8   // node partitions, bound to XCD via p = blockIdx&7 (heuristic)
#define SEGE 4096 // edges per scatter segment (256 threads x 16 edges)
#define ABLK 8    // agg: nodes per block (1 node per half-wave -> 12.5K blocks TLP)

typedef __attribute__((ext_vector_type(8))) short bf16x8;
typedef __attribute__((ext_vector_type(4))) float f32x4;

__device__ __forceinline__ unsigned short f2bf(float f) {
  unsigned u = __float_as_uint(f);
  u += 0x7fffu + ((u >> 16) & 1u);
  return (unsigned short)(u >> 16);
}

// ---------- FUSED: XCD-bound partitioned scatter + MFMA gemm (round-10, 52us) ----------
__global__ __launch_bounds__(256) void k_fused(
    const float* __restrict__ X, const float* __restrict__ W,
    const float* __restrict__ B, unsigned short* __restrict__ hb, int N, int Gg,
    const int2* __restrict__ ei, int* __restrict__ cnt,
    int* __restrict__ ell_t, int E) {
  __shared__ float WtF[4096];  // 16 KB: Wt[col][k] bf16, XOR-swizzled

  int bid = blockIdx.x;
  int tid = threadIdx.x;
  int gid = bid >> 4;
  int slot = bid & 15;

  if (slot < 8) {
    // ----- scatter role: partition p = bid&7 (XCD-bound), segment = gid -----
    int p = slot;
    int lo = (int)((long long)p * N / NPART);
    int hi = (int)((long long)(p + 1) * N / NPART);
    const int4* e4 = (const int4*)ei;
    int n4 = E >> 1;
    int base4 = gid * (SEGE / 2);
    #pragma unroll
    for (int i = 0; i < 8; ++i) {
      int q = base4 + i * 256 + tid;
      if (q < n4) {
        int4 v = e4[q];                   // 2 edges, coalesced
        if (v.x >= lo && v.x < hi) {
          int pos = atomicAdd(&cnt[v.x], 1);
          if (pos < CAP) ell_t[(size_t)pos * N + v.x] = v.y;
        }
        if (v.z >= lo && v.z < hi) {
          int pos = atomicAdd(&cnt[v.z], 1);
          if (pos < CAP) ell_t[(size_t)pos * N + v.z] = v.w;
        }
      }
    }
    if ((E & 1) && gid == 0 && tid == 0) {
      int2 sd = ei[E - 1];
      if (sd.x >= lo && sd.x < hi) {
        int pos = atomicAdd(&cnt[sd.x], 1);
        if (pos < CAP) ell_t[(size_t)pos * N + sd.x] = sd.y;
      }
    }
    return;
  }

  // ----- gemm role: hb = bf16(X@W + b) via MFMA, 64 rows x 64 cols per block -----
  int tile = gid * 8 + (slot - 8);
  if (tile >= Gg) return;

  char* Wt = (char*)WtF;
  const float4* W4 = (const float4*)W;
  for (int i = tid; i < 2048; i += 256) {
    float4 v = W4[i];
    int k = i >> 4;
    int col0 = (i & 15) << 2;
    int kb2 = k << 1;
    *(unsigned short*)(Wt + (((col0 + 0) << 8) | (kb2 ^ (((col0 + 0) & 7) << 4)))) = f2bf(v.x);
    *(unsigned short*)(Wt + (((col0 + 1) << 8) | (kb2 ^ (((col0 + 1) & 7) << 4)))) = f2bf(v.y);
    *(unsigned short*)(Wt + (((col0 + 2) << 8) | (kb2 ^ (((col0 + 2) & 7) << 4)))) = f2bf(v.z);
    *(unsigned short*)(Wt + (((col0 + 3) << 8) | (kb2 ^ (((col0 + 3) & 7) << 4)))) = f2bf(v.w);
  }
  __syncthreads();

  int lane = tid & 63;
  int w = tid >> 6;
  int l15 = lane & 15;
  int lk = lane >> 4;

  int row0 = tile * 64;
  int rA = row0 + w * 16 + l15;
  bool rowok = rA < N;
  const float* xp = X + (size_t)rA * 128 + (lk << 3);

  f32x4 acc[4];
  #pragma unroll
  for (int n = 0; n < 4; ++n) {
    float bv = B[(n << 4) + l15];
    acc[n] = (f32x4){bv, bv, bv, bv};
  }

  #pragma unroll
  for (int kb = 0; kb < 4; ++kb) {
    bf16x8 af = {0, 0, 0, 0, 0, 0, 0, 0};
    if (rowok) {
      float4 x0 = *(const float4*)(xp + kb * 32);
      float4 x1 = *(const float4*)(xp + kb * 32 + 4);
      af[0] = (short)f2bf(x0.x); af[1] = (short)f2bf(x0.y);
      af[2] = (short)f2bf(x0.z); af[3] = (short)f2bf(x0.w);
      af[4] = (short)f2bf(x1.x); af[5] = (short)f2bf(x1.y);
      af[6] = (short)f2bf(x1.z); af[7] = (short)f2bf(x1.w);
    }
    int kbyte = (kb << 6) | (lk << 4);
    #pragma unroll
    for (int n = 0; n < 4; ++n) {
      int col = (n << 4) + l15;
      bf16x8 bfr = *(const bf16x8*)(Wt + ((col << 8) | (kbyte ^ ((col & 7) << 4))));
      acc[n] = __builtin_amdgcn_mfma_f32_16x16x32_bf16(af, bfr, acc[n], 0, 0, 0);
    }
  }

  // C/D layout (verified m89/m91): col = lane&15, row = (lane>>4)*4 + reg
  int rbase = row0 + w * 16 + (lk << 2);
  #pragma unroll
  for (int n = 0; n < 4; ++n) {
    #pragma unroll
    for (int q = 0; q < 4; ++q) {
      int row = rbase + q;
      if (row < N) hb[(size_t)row * 64 + (n << 4) + l15] = f2bf(acc[n][q]);
    }
  }
}

// ---------- aggregate + self + BN: 1 node per HALF-WAVE, 8 nodes/block ----------
// 12.5K blocks (8x prior TLP); staging is exactly ONE coalesced 256-thread read
// (lds_dst[p][j], 1KB); per-node chain is one 8-wide gather batch + tail. cnt
// loads are half-wave-uniform broadcasts (cnt L2-resident).
__global__ __launch_bounds__(256) void k_agg(const int* __restrict__ cnt,
                                             const int* __restrict__ ell_t,
                                             const unsigned int* __restrict__ hb32,
                                             const float* __restrict__ gamma,
                                             const float* __restrict__ beta,
                                             const float* __restrict__ mean,
                                             const float* __restrict__ var,
                                             float* __restrict__ out, int N) {
  __shared__ int lds_dst[CAP * ABLK];   // [p][j], 1 KB

  int tid = threadIdx.x;
  int node0 = blockIdx.x * ABLK;

  // one staging read per thread: p = tid>>3, j = tid&7 (CAP*ABLK == 256)
  {
    int j = tid & (ABLK - 1);
    int p = tid >> 3;
    int n = node0 + j;
    lds_dst[p * ABLK + j] = (n < N) ? ell_t[(size_t)p * N + n] : 0;
  }

  int hw = tid >> 5;    // node within block
  int fp = tid & 31;    // feature-pair index
  int node = node0 + hw;

  float2 gm = *(const float2*)&gamma[fp * 2];
  float2 bt = *(const float2*)&beta[fp * 2];
  float2 mn = *(const float2*)&mean[fp * 2];
  float2 vr = *(const float2*)&var[fp * 2];
  float gsx = gm.x * rsqrtf(vr.x + BN_EPS);
  float gsy = gm.y * rsqrtf(vr.y + BN_EPS);

  __syncthreads();
  if (node >= N) return;

  int c0 = cnt[node];                         // half-wave-uniform, L2-resident
  int c = (c0 < CAP) ? c0 : CAP;
  unsigned us = hb32[(size_t)node * 32 + fp]; // self row, issue early

  float ax = 0.f, ay = 0.f;
  int q = 0;
  for (; q + 8 <= c; q += 8) {
    int d[8];
    #pragma unroll
    for (int i = 0; i < 8; ++i) {
      int dr = lds_dst[(q + i) * ABLK + hw];
      d[i] = ((unsigned)dr < (unsigned)N) ? dr : 0;
    }
    int cc[8];
    #pragma unroll
    for (int i = 0; i < 8; ++i) cc[i] = cnt[d[i]];
    unsigned u[8];
    #pragma unroll
    for (int i = 0; i < 8; ++i) u[i] = hb32[(size_t)d[i] * 32 + fp];
    #pragma unroll
    for (int i = 0; i < 8; ++i) {
      float s = rsqrtf((float)((cc[i] > 0) ? cc[i] : 1));
      ax = fmaf(s, __uint_as_float(u[i] << 16), ax);
      ay = fmaf(s, __uint_as_float(u[i] & 0xffff0000u), ay);
    }
  }
  if (q + 4 <= c) {
    int d0 = lds_dst[(q + 0) * ABLK + hw]; d0 = ((unsigned)d0 < (unsigned)N) ? d0 : 0;
    int d1 = lds_dst[(q + 1) * ABLK + hw]; d1 = ((unsigned)d1 < (unsigned)N) ? d1 : 0;
    int d2 = lds_dst[(q + 2) * ABLK + hw]; d2 = ((unsigned)d2 < (unsigned)N) ? d2 : 0;
    int d3 = lds_dst[(q + 3) * ABLK + hw]; d3 = ((unsigned)d3 < (unsigned)N) ? d3 : 0;
    int c0_ = cnt[d0], c1_ = cnt[d1], c2_ = cnt[d2], c3_ = cnt[d3];
    unsigned u0 = hb32[(size_t)d0 * 32 + fp];
    unsigned u1 = hb32[(size_t)d1 * 32 + fp];
    unsigned u2 = hb32[(size_t)d2 * 32 + fp];
    unsigned u3 = hb32[(size_t)d3 * 32 + fp];
    float s0 = rsqrtf((float)((c0_ > 0) ? c0_ : 1));
    float s1 = rsqrtf((float)((c1_ > 0) ? c1_ : 1));
    float s2 = rsqrtf((float)((c2_ > 0) ? c2_ : 1));
    float s3 = rsqrtf((float)((c3_ > 0) ? c3_ : 1));
    ax = fmaf(s0, __uint_as_float(u0 << 16), ax);
    ay = fmaf(s0, __uint_as_float(u0 & 0xffff0000u), ay);
    ax = fmaf(s1, __uint_as_float(u1 << 16), ax);
    ay = fmaf(s1, __uint_as_float(u1 & 0xffff0000u), ay);
    ax = fmaf(s2, __uint_as_float(u2 << 16), ax);
    ay = fmaf(s2, __uint_as_float(u2 & 0xffff0000u), ay);
    ax = fmaf(s3, __uint_as_float(u3 << 16), ax);
    ay = fmaf(s3, __uint_as_float(u3 & 0xffff0000u), ay);
    q += 4;
  }
  for (; q < c; ++q) {
    int dq = lds_dst[q * ABLK + hw];
    dq = ((unsigned)dq < (unsigned)N) ? dq : 0;
    int cq = cnt[dq];
    unsigned u = hb32[(size_t)dq * 32 + fp];
    float sq = rsqrtf((float)((cq > 0) ? cq : 1));
    ax = fmaf(sq, __uint_as_float(u << 16), ax);
    ay = fmaf(sq, __uint_as_float(u & 0xffff0000u), ay);
  }

  float hx = __uint_as_float(us << 16);
  float hy = __uint_as_float(us & 0xffff0000u);
  float degf = (float)c0;
  float isd_n = rsqrtf((float)((c0 > 0) ? c0 : 1));
  float rx = 0.5f * (isd_n * ax + degf * hx);
  float ry = 0.5f * (isd_n * ay + degf * hy);

  float2 o;
  o.x = (rx - mn.x) * gsx + bt.x;
  o.y = (ry - mn.y) * gsy + bt.y;
  *(float2*)&out[(size_t)node * 64 + fp * 2] = o;
}

extern "C" void kernel_launch(void* const* d_in, const int* in_sizes, int n_in,
                              void* d_out, int out_size, void* d_ws, size_t ws_size,
                              hipStream_t stream) {
  const float* X     = (const float*)d_in[0];
  const float* W     = (const float*)d_in[1];
  const float* B     = (const float*)d_in[2];
  const float* gamma = (const float*)d_in[3];
  const float* beta  = (const float*)d_in[4];
  const float* mean  = (const float*)d_in[5];
  const float* var   = (const float*)d_in[6];
  const int2*  ei    = (const int2*)d_in[7];

  int N = in_sizes[0] / 128;
  int E = in_sizes[7] / 2;
  float* out = (float*)d_out;

  // workspace: hb (N*64 bf16 = 12.8MB) | ell_t (N*CAP int = 12.8MB) | cnt (N int)
  unsigned short* hb  = (unsigned short*)d_ws;
  int*            ell = (int*)(hb + (size_t)N * 64);
  int*            cnt = ell + (size_t)N * CAP;

  (void)hipMemsetAsync(cnt, 0, (size_t)N * sizeof(int), stream);

  int Gg = (N + 63) / 64;                       // gemm tiles
  int nsegs = (E + SEGE - 1) / SEGE;            // scatter segments (x8 partitions)
  int ngg = (Gg + 7) / 8;                       // gemm groups
  int ngroups = (nsegs > ngg) ? nsegs : ngg;
  k_fused<<<ngroups * 16, 256, 0, stream>>>(X, W, B, hb, N, Gg, ei, cnt, ell, E);

  int Ga = (N + ABLK - 1) / ABLK;               // agg blocks (8 nodes each)
  k_agg<<<Ga, 256, 0, stream>>>(cnt, ell, (const unsigned int*)hb,
                                gamma, beta, mean, var, out, N);
}

// Round 12
// 171.354 us; speedup vs baseline: 1.0792x; 1.0270x over previous
//
#include <hip/hip_runtime.h>

#define BN_EPS 0.001f
#define CAP 32    // deg = 1 + Poisson(~9); P(deg >= 32) ~ 1e-22 -> safe
#define NPART 8   // node partitions, bound to XCD via p = blockIdx&7 (heuristic)
#define SEGE 4096 // edges per scatter segment (256 threads x 16 edges)
#define ABLK 8    // agg: nodes per block (1 node per half-wave)

typedef __attribute__((ext_vector_type(8))) short bf16x8;
typedef __attribute__((ext_vector_type(4))) float f32x4;

__device__ __forceinline__ unsigned short f2bf(float f) {
  unsigned u = __float_as_uint(f);
  u += 0x7fffu + ((u >> 16) & 1u);
  return (unsigned short)(u >> 16);
}
__device__ __forceinline__ float bfLO(unsigned u) { return __uint_as_float(u << 16); }
__device__ __forceinline__ float bfHI(unsigned u) { return __uint_as_float(u & 0xffff0000u); }

// ---------- FUSED: XCD-bound partitioned scatter + MFMA gemm (round-10/11, ~51us) ----------
__global__ __launch_bounds__(256) void k_fused(
    const float* __restrict__ X, const float* __restrict__ W,
    const float* __restrict__ B, unsigned short* __restrict__ hb, int N, int Gg,
    const int2* __restrict__ ei, int* __restrict__ cnt,
    int* __restrict__ ell_t, int E) {
  __shared__ float WtF[4096];  // 16 KB: Wt[col][k] bf16, XOR-swizzled

  int bid = blockIdx.x;
  int tid = threadIdx.x;
  int gid = bid >> 4;
  int slot = bid & 15;

  if (slot < 8) {
    // ----- scatter role: partition p = bid&7 (XCD-bound), segment = gid -----
    int p = slot;
    int lo = (int)((long long)p * N / NPART);
    int hi = (int)((long long)(p + 1) * N / NPART);
    const int4* e4 = (const int4*)ei;
    int n4 = E >> 1;
    int base4 = gid * (SEGE / 2);
    #pragma unroll
    for (int i = 0; i < 8; ++i) {
      int q = base4 + i * 256 + tid;
      if (q < n4) {
        int4 v = e4[q];                   // 2 edges, coalesced
        if (v.x >= lo && v.x < hi) {
          int pos = atomicAdd(&cnt[v.x], 1);
          if (pos < CAP) ell_t[(size_t)pos * N + v.x] = v.y;
        }
        if (v.z >= lo && v.z < hi) {
          int pos = atomicAdd(&cnt[v.z], 1);
          if (pos < CAP) ell_t[(size_t)pos * N + v.z] = v.w;
        }
      }
    }
    if ((E & 1) && gid == 0 && tid == 0) {
      int2 sd = ei[E - 1];
      if (sd.x >= lo && sd.x < hi) {
        int pos = atomicAdd(&cnt[sd.x], 1);
        if (pos < CAP) ell_t[(size_t)pos * N + sd.x] = sd.y;
      }
    }
    return;
  }

  // ----- gemm role: hb = bf16(X@W + b) via MFMA, 64 rows x 64 cols per block -----
  int tile = gid * 8 + (slot - 8);
  if (tile >= Gg) return;

  char* Wt = (char*)WtF;
  const float4* W4 = (const float4*)W;
  for (int i = tid; i < 2048; i += 256) {
    float4 v = W4[i];
    int k = i >> 4;
    int col0 = (i & 15) << 2;
    int kb2 = k << 1;
    *(unsigned short*)(Wt + (((col0 + 0) << 8) | (kb2 ^ (((col0 + 0) & 7) << 4)))) = f2bf(v.x);
    *(unsigned short*)(Wt + (((col0 + 1) << 8) | (kb2 ^ (((col0 + 1) & 7) << 4)))) = f2bf(v.y);
    *(unsigned short*)(Wt + (((col0 + 2) << 8) | (kb2 ^ (((col0 + 2) & 7) << 4)))) = f2bf(v.z);
    *(unsigned short*)(Wt + (((col0 + 3) << 8) | (kb2 ^ (((col0 + 3) & 7) << 4)))) = f2bf(v.w);
  }
  __syncthreads();

  int lane = tid & 63;
  int w = tid >> 6;
  int l15 = lane & 15;
  int lk = lane >> 4;

  int row0 = tile * 64;
  int rA = row0 + w * 16 + l15;
  bool rowok = rA < N;
  const float* xp = X + (size_t)rA * 128 + (lk << 3);

  f32x4 acc[4];
  #pragma unroll
  for (int n = 0; n < 4; ++n) {
    float bv = B[(n << 4) + l15];
    acc[n] = (f32x4){bv, bv, bv, bv};
  }

  #pragma unroll
  for (int kb = 0; kb < 4; ++kb) {
    bf16x8 af = {0, 0, 0, 0, 0, 0, 0, 0};
    if (rowok) {
      float4 x0 = *(const float4*)(xp + kb * 32);
      float4 x1 = *(const float4*)(xp + kb * 32 + 4);
      af[0] = (short)f2bf(x0.x); af[1] = (short)f2bf(x0.y);
      af[2] = (short)f2bf(x0.z); af[3] = (short)f2bf(x0.w);
      af[4] = (short)f2bf(x1.x); af[5] = (short)f2bf(x1.y);
      af[6] = (short)f2bf(x1.z); af[7] = (short)f2bf(x1.w);
    }
    int kbyte = (kb << 6) | (lk << 4);
    #pragma unroll
    for (int n = 0; n < 4; ++n) {
      int col = (n << 4) + l15;
      bf16x8 bfr = *(const bf16x8*)(Wt + ((col << 8) | (kbyte ^ ((col & 7) << 4))));
      acc[n] = __builtin_amdgcn_mfma_f32_16x16x32_bf16(af, bfr, acc[n], 0, 0, 0);
    }
  }

  // C/D layout (verified m89/m91): col = lane&15, row = (lane>>4)*4 + reg
  int rbase = row0 + w * 16 + (lk << 2);
  #pragma unroll
  for (int n = 0; n < 4; ++n) {
    #pragma unroll
    for (int q = 0; q < 4; ++q) {
      int row = rbase + q;
      if (row < N) hb[(size_t)row * 64 + (n << 4) + l15] = f2bf(acc[n][q]);
    }
  }
}

// ---------- aggregate + self + BN: 1 node/half-wave, 2 EDGES PER STEP ----------
// Lanes 0-15 service edge 2q (8B uint2 each), lanes 16-31 edge 2q+1: hb-gather,
// cnt-load, and LDS-read instruction counts all HALVE vs round 11 (FMA count
// unchanged). Pair-combine via __shfl_xor(.,16); 16-lane float4 out-write.
__global__ __launch_bounds__(256) void k_agg(const int* __restrict__ cnt,
                                             const int* __restrict__ ell_t,
                                             const uint2* __restrict__ hb64,
                                             const float* __restrict__ gamma,
                                             const float* __restrict__ beta,
                                             const float* __restrict__ mean,
                                             const float* __restrict__ var,
                                             float* __restrict__ out, int N) {
  __shared__ int lds_dst[CAP * ABLK];   // [p][j], 1 KB

  int tid = threadIdx.x;
  int node0 = blockIdx.x * ABLK;

  // one staging read per thread: p = tid>>3, j = tid&7 (CAP*ABLK == 256)
  {
    int j = tid & (ABLK - 1);
    int p = tid >> 3;
    int n = node0 + j;
    lds_dst[p * ABLK + j] = (n < N) ? ell_t[(size_t)p * N + n] : 0;
  }

  int hw = tid >> 5;          // node within block
  int lane32 = tid & 31;
  int sl = lane32 & 15;       // qword (8B) index within 128B hb row
  int hf = lane32 >> 4;       // which edge of the pair this lane services
  int node = node0 + hw;

  // BN params for features 4sl..4sl+3
  float4 gm = *(const float4*)&gamma[sl * 4];
  float4 bt = *(const float4*)&beta[sl * 4];
  float4 mn = *(const float4*)&mean[sl * 4];
  float4 vr = *(const float4*)&var[sl * 4];
  float gs0 = gm.x * rsqrtf(vr.x + BN_EPS);
  float gs1 = gm.y * rsqrtf(vr.y + BN_EPS);
  float gs2 = gm.z * rsqrtf(vr.z + BN_EPS);
  float gs3 = gm.w * rsqrtf(vr.w + BN_EPS);

  __syncthreads();
  if (node >= N) return;

  int c0 = cnt[node];                          // half-wave-uniform, L2-resident
  int c = (c0 < CAP) ? c0 : CAP;
  uint2 us = hb64[(size_t)node * 16 + sl];     // self row, issue early

  float a0 = 0.f, a1 = 0.f, a2 = 0.f, a3 = 0.f;
  int npair = (c + 1) >> 1;
  int pq = 0;
  for (; pq + 4 <= npair; pq += 4) {           // 8 edges per iteration
    int d[4]; float vmask[4];
    #pragma unroll
    for (int i = 0; i < 4; ++i) {
      int e = 2 * (pq + i) + hf;
      bool vld = e < c;
      int dr = vld ? lds_dst[e * ABLK + hw] : 0;
      d[i] = ((unsigned)dr < (unsigned)N) ? dr : 0;
      vmask[i] = vld ? 1.f : 0.f;
    }
    int cc[4];
    #pragma unroll
    for (int i = 0; i < 4; ++i) cc[i] = cnt[d[i]];
    uint2 u[4];
    #pragma unroll
    for (int i = 0; i < 4; ++i) u[i] = hb64[(size_t)d[i] * 16 + sl];
    #pragma unroll
    for (int i = 0; i < 4; ++i) {
      float s = vmask[i] * rsqrtf((float)((cc[i] > 0) ? cc[i] : 1));
      a0 = fmaf(s, bfLO(u[i].x), a0);
      a1 = fmaf(s, bfHI(u[i].x), a1);
      a2 = fmaf(s, bfLO(u[i].y), a2);
      a3 = fmaf(s, bfHI(u[i].y), a3);
    }
  }
  for (; pq < npair; ++pq) {
    int e = 2 * pq + hf;
    bool vld = e < c;
    int dr = vld ? lds_dst[e * ABLK + hw] : 0;
    int d = ((unsigned)dr < (unsigned)N) ? dr : 0;
    int cq = cnt[d];
    uint2 u = hb64[(size_t)d * 16 + sl];
    float s = (vld ? 1.f : 0.f) * rsqrtf((float)((cq > 0) ? cq : 1));
    a0 = fmaf(s, bfLO(u.x), a0);
    a1 = fmaf(s, bfHI(u.x), a1);
    a2 = fmaf(s, bfLO(u.y), a2);
    a3 = fmaf(s, bfHI(u.y), a3);
  }

  // combine even-edge (hf=0) and odd-edge (hf=1) partial sums
  a0 += __shfl_xor(a0, 16);
  a1 += __shfl_xor(a1, 16);
  a2 += __shfl_xor(a2, 16);
  a3 += __shfl_xor(a3, 16);

  float degf = (float)c0;
  float isd = rsqrtf((float)((c0 > 0) ? c0 : 1));
  float r0 = 0.5f * (isd * a0 + degf * bfLO(us.x));
  float r1 = 0.5f * (isd * a1 + degf * bfHI(us.x));
  float r2 = 0.5f * (isd * a2 + degf * bfLO(us.y));
  float r3 = 0.5f * (isd * a3 + degf * bfHI(us.y));

  if (hf == 0) {
    float4 o;
    o.x = (r0 - mn.x) * gs0 + bt.x;
    o.y = (r1 - mn.y) * gs1 + bt.y;
    o.z = (r2 - mn.z) * gs2 + bt.z;
    o.w = (r3 - mn.w) * gs3 + bt.w;
    *(float4*)&out[(size_t)node * 64 + sl * 4] = o;   // 16 lanes x 16B = 256B row
  }
}

extern "C" void kernel_launch(void* const* d_in, const int* in_sizes, int n_in,
                              void* d_out, int out_size, void* d_ws, size_t ws_size,
                              hipStream_t stream) {
  const float* X     = (const float*)d_in[0];
  const float* W     = (const float*)d_in[1];
  const float* B     = (const float*)d_in[2];
  const float* gamma = (const float*)d_in[3];
  const float* beta  = (const float*)d_in[4];
  const float* mean  = (const float*)d_in[5];
  const float* var   = (const float*)d_in[6];
  const int2*  ei    = (const int2*)d_in[7];

  int N = in_sizes[0] / 128;
  int E = in_sizes[7] / 2;
  float* out = (float*)d_out;

  // workspace: hb (N*64 bf16 = 12.8MB) | ell_t (N*CAP int = 12.8MB) | cnt (N int)
  unsigned short* hb  = (unsigned short*)d_ws;
  int*            ell = (int*)(hb + (size_t)N * 64);
  int*            cnt = ell + (size_t)N * CAP;

  (void)hipMemsetAsync(cnt, 0, (size_t)N * sizeof(int), stream);

  int Gg = (N + 63) / 64;                       // gemm tiles
  int nsegs = (E + SEGE - 1) / SEGE;            // scatter segments (x8 partitions)
  int ngg = (Gg + 7) / 8;                       // gemm groups
  int ngroups = (nsegs > ngg) ? nsegs : ngg;
  k_fused<<<ngroups * 16, 256, 0, stream>>>(X, W, B, hb, N, Gg, ei, cnt, ell, E);

  int Ga = (N + ABLK - 1) / ABLK;               // agg blocks (8 nodes each)
  k_agg<<<Ga, 256, 0, stream>>>(cnt, ell, (const uint2*)hb,
                                gamma, beta, mean, var, out, N);
}